// Round 15
// baseline (54.461 us; speedup 1.0000x reference)
//
#include <hip/hip_runtime.h>

// (B,C,H,W) = (8,19,512,512), fp32 everywhere.
constexpr int B_ = 8, C_ = 19, H_ = 512, W_ = 512;
constexpr int HW_ = H_ * W_;
constexpr int NT = 512;
constexpr int QH = 128, QW = 128;   // quarter resolution

// K1 LDS layout (floats): sgq 20x142 at 0; t2q 6x142 at 2944; whq 6x130 at 3840;
// A-table 512 at 4640; saw 19 at 5152. Total 5184 floats = 20.7 KB.
constexpr int T2Q_OFF = 2944, WHQ_OFF = 3840, A_OFF = 4640, SAW_OFF = 5152;
constexpr int K1_LDSF = 5184;
// K2 LDS: st 8x540 = 4320 floats
constexpr int ST_S = 540;

// workspace offsets (floats):
constexpr long WS_BM   = 0;      // blockmax (z*32+ht), z = eye*8+b
constexpr long WS_EW   = 512;    // eyesumw
constexpr long WS_ESUM = 1024;   // esum: 1024 entries (b*128 + halfchunk)
constexpr long WS_DSG  = 4096;                    // dsg: 16 x 128 x 128
constexpr long WS_T0   = WS_DSG + 16L * QH * QW;  // t0: 24 images (w_l, w_r, t3)

__device__ __forceinline__ int refl(int i, int n) {
    i = (i < 0) ? -i : i;
    return (i >= n) ? (2 * n - 2 - i) : i;
}

template<int ND>
__device__ __forceinline__ void gauss_reg(float (&wkr)[ND], float sigma) {
    float s = 0.f;
#pragma unroll
    for (int d = 0; d < ND; ++d) {
        const float t = d / sigma;
        wkr[d] = expf(-0.5f * t * t);
        s += (d ? 2.f : 1.f) * wkr[d];
    }
    const float inv = 1.f / s;
#pragma unroll
    for (int d = 0; d < ND; ++d) wkr[d] *= inv;
}

// Total-contribution weight of input position i under the K=21 reflect blur.
__device__ __forceinline__ float aweight(int i, const float (&wkr)[11]) {
    float a = 0.f;
#pragma unroll
    for (int t = 0; t < 21; ++t) {
        const float k = wkr[(t < 10) ? (10 - t) : (t - 10)];
        const int o = i + 10 - t;
        if (o >= 0 && o < H_) a += k;
        if (i >= 1 && i <= 10 && t <= 10 - i) a += k;
        if (i >= 501 && i <= 510 && t >= 521 - i) a += k;
    }
    return a;
}

// ===================== K0: box4 downsample of OWNED rows =====================
__global__ void __launch_bounds__(NT)
k0_ds(const float* __restrict__ mp, float* __restrict__ ws)
{
    float* dsg = ws + WS_DSG;
    const int bid = blockIdx.x, tid = threadIdx.x;
    const int vb = (bid & 7) * 64 + (bid >> 3);
    const int b = vb >> 6, eye = (vb >> 5) & 1, ht = vb & 31;
    const int z = eye * 8 + b;
    const float* sb = mp + ((long)b * C_ + 4 + eye) * HW_;
    const int q = tid >> 7, cg = tid & 127;
    const int fr = ht * 16 + q * 4;
    float s = 0.f;
#pragma unroll
    for (int r = 0; r < 4; ++r) {
        const float4 v = *(const float4*)(sb + (long)(fr + r) * W_ + 4 * cg);
        s += (v.x + v.y) + (v.z + v.w);
    }
    dsg[(long)z * (QH * QW) + (long)(ht * 4 + q) * QW + cg] = s * 0.0625f;
}

// ========== eye role: quarter-res blur + upsample + mask + max/sum ==========
__device__ __forceinline__ void eye_q(const float* __restrict__ mp,
                                      const float* __restrict__ dsg,
                                      float* __restrict__ t0,
                                      float* __restrict__ blockmax,
                                      float* __restrict__ eyesumw,
                                      float* lds, int tid, int vb)
{
    float kq[8];
    gauss_reg(kq, 3.75f);                     // quarter-res sigma = 15/4, K=15
    const int b = vb >> 6, eye = (vb >> 5) & 1, ht = vb & 31;
    const int z = eye * 8 + b;
    const float* dz = dsg + (long)z * (QH * QW);

    // stage dsg rows [4ht-8, 4ht+12) with 7-col reflect halo -> sgq[20][142]
    float* sgq = lds;
    for (int t = 0; t < 6; ++t) {
        const int e = tid + t * NT;
        if (e < 20 * 142) {
            const int r = e / 142, c = e - r * 142;
            sgq[r * 142 + c] = dz[(long)refl(ht * 4 - 8 + r, QH) * QW + refl(c - 7, QW)];
        }
    }
    __syncthreads();
    // H-blur: 426 threads x 2 rows (register window 16) -> t2q[6][142]
    float* t2q = lds + T2Q_OFF;
    if (tid < 426) {
        const int g = tid / 142, c = tid - g * 142;
        float w[16];
#pragma unroll
        for (int s = 0; s < 16; ++s) w[s] = sgq[(2 * g + s) * 142 + c];
#pragma unroll
        for (int jr = 0; jr < 2; ++jr) {
            float a = 0.f;
#pragma unroll
            for (int d = 0; d < 15; ++d)
                a = fmaf(w[jr + d], kq[(d < 7) ? (7 - d) : (d - 7)], a);
            t2q[(2 * g + jr) * 142 + c] = a;
        }
    }
    __syncthreads();
    // W-blur -> whq[6][130] (quarter col j stored at +1; 0/129 replicated)
    float* whq = lds + WHQ_OFF;
#pragma unroll
    for (int t = 0; t < 2; ++t) {
        const int e = tid + t * NT;
        if (e < 768) {
            const int s = e >> 7, c = e & 127;
            float a = 0.f;
#pragma unroll
            for (int d = 0; d < 15; ++d)
                a = fmaf(t2q[s * 142 + c + d], kq[(d < 7) ? (7 - d) : (d - 7)], a);
            whq[s * 130 + c + 1] = a;
        }
    }
    __syncthreads();
    if (tid < 6) {
        whq[tid * 130]       = whq[tid * 130 + 1];
        whq[tid * 130 + 129] = whq[tid * 130 + 128];
    }
    __syncthreads();
    if (ht == 0 && tid < 130)  whq[tid]           = whq[130 + tid];
    if (ht == 31 && tid < 130) whq[5 * 130 + tid] = whq[4 * 130 + tid];
    __syncthreads();

    // S4: factor-4 bilinear upsample + mask + write v + per-block max/A-sum
    const float* A = lds + A_OFF;
    const int c = tid;
    const int j = ((c + 2) >> 2) - 1;         // -1..127 (stored at j+1)
    const float fc = 0.625f + 0.25f * (float)(c & 1) - 0.5f * (float)((c >> 1) & 1);
    float cv[6];
#pragma unroll
    for (int s = 0; s < 6; ++s) {
        const float a0 = whq[s * 130 + j + 1], a1 = whq[s * 130 + j + 2];
        cv[s] = fmaf(fc, a1 - a0, a0);
    }
    const float Aw = A[c];
    const long mbase = (long)b * C_ * HW_ + (long)(ht * 16) * W_ + c;
    const float* eyp = mp + mbase + (long)(4 + eye) * HW_;
    const float* bgp = mp + mbase;
    float* db = t0 + (long)z * HW_ + (long)(ht * 16) * W_ + c;
    float vmax = 0.f, vsum = 0.f;
#pragma unroll
    for (int o = 0; o < 16; ++o) {
        const int ls0 = (o + 2) >> 2;         // static 0..4
        const float fr_ = 0.625f + 0.25f * (float)(o & 1) - 0.5f * (float)((o >> 1) & 1);
        const float wv = fmaf(fr_, cv[ls0 + 1] - cv[ls0], cv[ls0]);
        const float ey = eyp[(long)o * W_], bg = bgp[(long)o * W_];
        const float v = wv * (1.f - ey) * (1.f - bg);
        db[(long)o * W_] = v;
        vmax = fmaxf(vmax, v);
        vsum = fmaf(v, A[ht * 16 + o] * Aw, vsum);
    }
#pragma unroll
    for (int off = 32; off; off >>= 1) {
        vmax = fmaxf(vmax, __shfl_down(vmax, off));
        vsum += __shfl_down(vsum, off);
    }
    __syncthreads();                          // sgq dead -> scratch ok
    if ((tid & 63) == 0) { lds[tid >> 6] = vmax; lds[8 + (tid >> 6)] = vsum; }
    __syncthreads();
    if (tid == 0) {
        float m = lds[0], s = lds[8];
        for (int i = 1; i < 8; ++i) { m = fmaxf(m, lds[i]); s += lds[8 + i]; }
        blockmax[z * 32 + ht] = m;
        eyesumw[z * 32 + ht] = s;
    }
}

// ========== einsum role: half-chunk (512 float4) + A-weighted sum ==========
__device__ __forceinline__ void einsum_half(const float* __restrict__ mp,
                                            float* __restrict__ t3,
                                            float* __restrict__ esum,
                                            float* lds, int tid, int idx)
{
    const float* A   = lds + A_OFF;
    const float* saw = lds + SAW_OFF;
    const int b = idx >> 7, ch = idx & 127;
    const int p4 = ch * 512 + tid;            // float4 index in batch
    const long p = (long)p4 * 4;
    const int h = (int)(p >> 9), w0 = (int)(p & 511);
    const float* mpb = mp + (long)b * C_ * HW_ + p;
    float4 acc = make_float4(0.f, 0.f, 0.f, 0.f);
#pragma unroll
    for (int c = 0; c < C_; ++c) {
        const float4 v = *(const float4*)(mpb + (long)c * HW_);
        const float a = saw[c];
        acc.x = fmaf(v.x, a, acc.x);
        acc.y = fmaf(v.y, a, acc.y);
        acc.z = fmaf(v.z, a, acc.z);
        acc.w = fmaf(v.w, a, acc.w);
    }
    *(float4*)(t3 + (long)b * HW_ + p) = acc;
    const float4 a4 = *(const float4*)(A + w0);
    float se = (acc.x * a4.x + acc.y * a4.y + acc.z * a4.z + acc.w * a4.w) * A[h];
#pragma unroll
    for (int off = 32; off; off >>= 1) se += __shfl_down(se, off);
    __syncthreads();
    if ((tid & 63) == 0) lds[tid >> 6] = se;
    __syncthreads();
    if (tid == 0) {
        float s = 0.f;
        for (int i = 0; i < 8; ++i) s += lds[i];
        esum[idx] = s;
    }
}

// ===================== K1: 1536 blocks (512 eye + 1024 einsum) ==============
__global__ void __launch_bounds__(NT, 8)
k1_mix(const float* __restrict__ mp, const float* __restrict__ aw,
       float* __restrict__ ws)
{
    __shared__ __align__(16) float lds[K1_LDSF];
    const int tid = threadIdx.x, bid = blockIdx.x;
    float* blockmax = ws + WS_BM;
    float* eyesumw  = ws + WS_EW;
    float* esum     = ws + WS_ESUM;
    float* dsg      = ws + WS_DSG;
    float* t0       = ws + WS_T0;
    float* t3       = t0 + 16L * HW_;

    {   // A-weight table + area weights (per-block)
        float w21[11];
        gauss_reg(w21, 2.f);
        lds[A_OFF + tid] = aweight(tid, w21);
    }
    if (tid < C_) lds[SAW_OFF + tid] = aw[tid];
    __syncthreads();

    if (bid < 512) {
        // eye role: XCD-keyed vb (b = bid&7)
        const int vb = (bid & 7) * 64 + (bid >> 3);
        eye_q(mp, dsg, t0, blockmax, eyesumw, lds, tid, vb);
    } else {
        // einsum role: XCD-keyed half-chunk (b = raw&7)
        const int raw = bid - 512;                    // 0..1023
        const int idx = (raw & 7) * 128 + (raw >> 3); // b*128 + halfchunk
        einsum_half(mp, t3, esum, lds, tid, idx);
    }
}

// ===================== K2: combine + 21-tap blur + scaled write =============
__global__ void __launch_bounds__(NT, 4)
k2_blur(const float* __restrict__ esw, float* __restrict__ out,
        float* __restrict__ ws)
{
    __shared__ __align__(16) float lds[ST_S * 8 + 32];
    const int tid = threadIdx.x, bid = blockIdx.x;
    const int vb = (bid & 7) * 64 + (bid >> 3);
    const float* blockmax = ws + WS_BM;
    const float* eyesumw  = ws + WS_EW;
    const float* esum     = ws + WS_ESUM;
    const float* t0       = ws + WS_T0;

    float wkr[11];
    gauss_reg(wkr, 2.f);
    const int b = vb >> 6, tile6 = vb & 63, hb = tile6 * 8;

    // uniform scalar reductions (identical in every thread)
    float mxL = blockmax[b * 32], mxR = blockmax[(8 + b) * 32];
    float SeL = 0.f, SeR = 0.f, Se = 0.f;
    for (int i = 0; i < 32; ++i) {
        mxL = fmaxf(mxL, blockmax[b * 32 + i]);
        mxR = fmaxf(mxR, blockmax[(8 + b) * 32 + i]);
        SeL += eyesumw[b * 32 + i];
        SeR += eyesumw[(8 + b) * 32 + i];
    }
    for (int i = 0; i < 128; ++i) Se += esum[b * 128 + i];
    const float e = esw[0];
    const float sl = e / mxL, sr = e / mxR;
    const float scale = (float)HW_ / (Se + sl * SeL + sr * SeR);

    const float* t1 = t0 + (long)b * HW_;
    const float* t2 = t0 + (long)(8 + b) * HW_;
    const float* t3 = t0 + (long)(16 + b) * HW_;

    // H-pass: thread = col, combine + 28-row window straight from global
    const int c = tid;
    float win[28];
#pragma unroll
    for (int i = 0; i < 28; ++i) {
        const long off = (long)refl(hb - 10 + i, H_) * W_ + c;
        win[i] = fmaf(t1[off], sl, fmaf(t2[off], sr, t3[off]));
    }
    float hv[8];
#pragma unroll
    for (int j = 0; j < 8; ++j) {
        float a = 0.f;
#pragma unroll
        for (int k = 0; k < 21; ++k)
            a = fmaf(win[j + k], wkr[(k < 10) ? (10 - k) : (k - 10)], a);
        hv[j] = a;
    }
    float* st = lds;                                   // 8 x 540, col x at 12+x
#pragma unroll
    for (int j = 0; j < 8; ++j) st[j * ST_S + 12 + c] = hv[j];
    __syncthreads();
    if (tid < 224) {                                   // 8 rows x 28 halo cols
        const int r = tid / 28, q = tid - r * 28;
        float* srow = st + r * ST_S;
        if (q < 12) srow[11 - q] = srow[13 + q];
        else { const int cc = q - 12; srow[524 + cc] = srow[522 - cc]; }
    }
    __syncthreads();
    // W-pass: wave = row, lane = 8-col group; b128 window reads
    {
        const int r = tid >> 6, g = tid & 63, c0 = g * 8;
        const float* srow = st + r * ST_S;             // col x at srow[12+x]
        float wn[32];                                  // cols c0-12 .. c0+19
#pragma unroll
        for (int m = 0; m < 8; ++m) {
            const float4 v = *(const float4*)(srow + c0 + 4 * m);
            wn[4*m] = v.x; wn[4*m+1] = v.y; wn[4*m+2] = v.z; wn[4*m+3] = v.w;
        }
        float oo[8];
#pragma unroll
        for (int o = 0; o < 8; ++o) {
            float a = 0.f;
#pragma unroll
            for (int k = 0; k < 21; ++k)
                a = fmaf(wn[o + 2 + k], wkr[(k < 10) ? (10 - k) : (k - 10)], a);
            oo[o] = a * scale;
        }
        float* orow = out + (long)b * HW_ + (long)(hb + r) * W_ + c0;
        *(float4*)(orow)     = make_float4(oo[0], oo[1], oo[2], oo[3]);
        *(float4*)(orow + 4) = make_float4(oo[4], oo[5], oo[6], oo[7]);
    }
}

extern "C" void kernel_launch(void* const* d_in, const int* in_sizes, int n_in,
                              void* d_out, int out_size, void* d_ws, size_t ws_size,
                              hipStream_t stream)
{
    const float* mp  = (const float*)d_in[0];  // (8,19,512,512) f32
    const float* aw  = (const float*)d_in[1];  // (19,) f32
    const float* esw = (const float*)d_in[2];  // (1,) f32
    float* out = (float*)d_out;                // (8,1,512,512) f32
    float* wsf = (float*)d_ws;

    k0_ds  <<<512,  NT, 0, stream>>>(mp, wsf);
    k1_mix <<<1536, NT, 0, stream>>>(mp, aw, wsf);
    k2_blur<<<512,  NT, 0, stream>>>(esw, out, wsf);
}